// Round 3
// baseline (209.826 us; speedup 1.0000x reference)
//
#include <hip/hip_runtime.h>

constexpr int IN_DIM   = 128;
constexpr int OUT_DIM  = 64;
constexpr int EDGE_DIM = 16;
constexpr int BS       = 8;
constexpr int NN       = 512;
constexpr int ROWS     = BS * NN;   // 4096
constexpr int TI       = 2;         // attention rows per block (2 waves/row)

// ---------------------------------------------------------------------------
// Kernel 1: h = x @ W^T  (h row-major (ROWS,64)),  s_j = h · a_j
// (s_i dropped: softmax over j is invariant to the per-i constant.)
// ---------------------------------------------------------------------------
__global__ __launch_bounds__(256, 4) void fc_kernel(
    const float* __restrict__ x, const float* __restrict__ W,
    const float* __restrict__ attn_w,
    float* __restrict__ h, float* __restrict__ sj)
{
    __shared__ float  xs[8 * IN_DIM];   // 4 KB
    __shared__ float4 ws[64 * 33];      // 33.8 KB (padded W, conflict-floor)
    const int t    = threadIdx.x;
    const int lane = t & 63;
    const int w    = t >> 6;
    const int rowBase = blockIdx.x * 8;

    ((float4*)xs)[t] = ((const float4*)(x + (size_t)rowBase * IN_DIM))[t];
    const float4* W4 = (const float4*)W;          // 2048 float4, coalesced
    #pragma unroll
    for (int i = 0; i < 8; ++i) {
        const int s = t + i * 256;
        ws[(s >> 5) * 33 + (s & 31)] = W4[s];
    }
    const float a_j = attn_w[OUT_DIM + lane];
    __syncthreads();

    const float4* xr0 = (const float4*)&xs[(w * 2 + 0) * IN_DIM];
    const float4* xr1 = (const float4*)&xs[(w * 2 + 1) * IN_DIM];
    float acc0 = 0.f, acc1 = 0.f;
    #pragma unroll 8
    for (int k = 0; k < IN_DIM / 4; ++k) {
        const float4 wv = ws[lane * 33 + k];
        const float4 x0 = xr0[k];
        const float4 x1 = xr1[k];
        acc0 += x0.x * wv.x + x0.y * wv.y + x0.z * wv.z + x0.w * wv.w;
        acc1 += x1.x * wv.x + x1.y * wv.y + x1.z * wv.z + x1.w * wv.w;
    }
    #pragma unroll
    for (int r = 0; r < 2; ++r) {
        const float a   = r ? acc1 : acc0;
        const int   row = rowBase + w * 2 + r;
        h[(size_t)row * OUT_DIM + lane] = a;
        float pj = a * a_j;
        #pragma unroll
        for (int m = 32; m > 0; m >>= 1) pj += __shfl_xor(pj, m, 64);
        if (lane == 0) sj[row] = pj;
    }
}

// ---------------------------------------------------------------------------
// Kernel 2: TI=2 rows per block, 2 waves per row (wave = {row, j-half}).
// 2048 blocks x 256 thr, 14.3 KB LDS, VGPR<=64 -> 8 blocks/CU = 32 waves/CU.
// Edge loads fully coalesced (1 KiB contiguous per wave instruction) via a
// 4-lane-per-j layout + quad shfl reduce. Softmax normalization folded into
// the epilogue (alpha kept unnormalized; out *= 1/sum at the end).
// ---------------------------------------------------------------------------
__global__ __launch_bounds__(256, 8) void attn_kernel(
    const float* __restrict__ edge, const float* __restrict__ attn_w,
    const float* __restrict__ h, const float* __restrict__ sj,
    float* __restrict__ out)
{
    __shared__ float  sjb[NN];            // 2 KB
    __shared__ float  alpha[TI * NN];     // 4 KB (e, then unnormalized p)
    __shared__ float4 part[TI][16][16];   // 8 KB
    __shared__ float  rm[TI][2], rs[TI][2];

    const int t    = threadIdx.x;
    const int lane = t & 63;
    const int w    = t >> 6;
    const int r    = w >> 1;              // local row 0..1
    const int hf   = w & 1;               // j-half 0..1
    const int blk  = blockIdx.x;
    const int b    = blk >> 8;
    const int itile = blk & 255;
    const size_t rowg = ((size_t)b << 9) + itile * TI + r;

    if (t < 128)                          // stage s_j for the whole batch
        ((float4*)sjb)[t] = ((const float4*)(sj + ((size_t)b << 9)))[t];

    const float4 aesel = ((const float4*)(attn_w + 2 * OUT_DIM))[lane & 3];
    const float4* ef4 = (const float4*)edge + rowg * (NN * EDGE_DIM / 4);
    __syncthreads();

    // ---- phase 1: e_j for this wave's 256 j's; 16 j per iteration ----
    const int jq = lane >> 2;             // 0..15: which j in the 16-group
    const int q  = lane & 3;              // quarter of the 16-wide edge vec
    float m = -1e30f;
    #pragma unroll 4
    for (int it = 0; it < 16; ++it) {
        const int j = hf * 256 + it * 16 + jq;
        const float4 v = ef4[j * 4 + q];  // wave: 1 KiB contiguous
        float pd = v.x * aesel.x + v.y * aesel.y + v.z * aesel.z + v.w * aesel.w;
        pd += __shfl_xor(pd, 1, 64);
        pd += __shfl_xor(pd, 2, 64);      // all 4 quad lanes hold full dot
        const float ev = pd + sjb[j];
        m = fmaxf(m, ev);
        if (q == 0) alpha[r * NN + j] = ev;   // 16 distinct banks
    }
    #pragma unroll
    for (int msk = 4; msk < 64; msk <<= 1) m = fmaxf(m, __shfl_xor(m, msk, 64));
    if (lane == 0) rm[r][hf] = m;
    __syncthreads();
    m = fmaxf(rm[r][0], rm[r][1]);        // row max across both halves

    // ---- pass 2: p = exp(e-m), row sum; alpha left UNnormalized ----
    float s = 0.f;
    #pragma unroll
    for (int k = 0; k < 4; ++k) {
        const int idx = r * NN + hf * 256 + k * 64 + lane;
        const float p = __expf(alpha[idx] - m);
        alpha[idx] = p;
        s += p;
    }
    #pragma unroll
    for (int msk = 1; msk < 64; msk <<= 1) s += __shfl_xor(s, msk, 64);
    if (lane == 0) rs[r][hf] = s;
    __syncthreads();                      // alpha + rs visible to all

    // ---- phase 3: out[r,:] = sum_j p[r][j] * h[b,j,:], h read once ----
    const int o4 = t & 15;                // float4 chunk of 64-dim output
    const int g  = t >> 4;                // 16 groups over j
    const float4* h4 = (const float4*)(h + (((size_t)b) << 9) * OUT_DIM);
    float4 acc0 = make_float4(0.f, 0.f, 0.f, 0.f);
    float4 acc1 = make_float4(0.f, 0.f, 0.f, 0.f);
    #pragma unroll 4
    for (int j = g; j < NN; j += 16) {
        const float4 hv = h4[j * 16 + o4];
        const float a0 = alpha[j];        // 16-lane broadcast
        const float a1 = alpha[NN + j];
        acc0.x += a0 * hv.x; acc0.y += a0 * hv.y;
        acc0.z += a0 * hv.z; acc0.w += a0 * hv.w;
        acc1.x += a1 * hv.x; acc1.y += a1 * hv.y;
        acc1.z += a1 * hv.z; acc1.w += a1 * hv.w;
    }
    part[0][g][o4] = acc0;
    part[1][g][o4] = acc1;
    __syncthreads();

    if (t < 32) {
        const int rr = t >> 4, c = t & 15;
        float4 v = part[rr][0][c];
        #pragma unroll
        for (int g2 = 1; g2 < 16; ++g2) {
            const float4 u = part[rr][g2][c];
            v.x += u.x; v.y += u.y; v.z += u.z; v.w += u.w;
        }
        const float rinv = 1.0f / (rs[rr][0] + rs[rr][1]);   // fold softmax norm
        v.x *= rinv; v.y *= rinv; v.z *= rinv; v.w *= rinv;
        ((float4*)out)[(((size_t)b << 9) + itile * TI + rr) * 16 + c] = v;
    }
}

extern "C" void kernel_launch(void* const* d_in, const int* in_sizes, int n_in,
                              void* d_out, int out_size, void* d_ws, size_t ws_size,
                              hipStream_t stream) {
    const float* x      = (const float*)d_in[0];
    const float* edge   = (const float*)d_in[1];
    const float* W_fc   = (const float*)d_in[2];
    const float* attn_w = (const float*)d_in[3];
    float* out = (float*)d_out;

    float* h  = (float*)d_ws;                   // ROWS*64 floats = 1 MiB
    float* sj = h + (size_t)ROWS * OUT_DIM;     // 16 KB

    fc_kernel<<<ROWS / 8, 256, 0, stream>>>(x, W_fc, attn_w, h, sj);
    attn_kernel<<<ROWS / TI, 256, 0, stream>>>(edge, attn_w, h, sj, out);
}

// Round 4
// 205.434 us; speedup vs baseline: 1.0214x; 1.0214x over previous
//
#include <hip/hip_runtime.h>

constexpr int IN_DIM   = 128;
constexpr int OUT_DIM  = 64;
constexpr int EDGE_DIM = 16;
constexpr int BS       = 8;
constexpr int NN       = 512;
constexpr int ROWS     = BS * NN;   // 4096
constexpr int TI       = 4;         // attention rows per block (1 wave/row)

// ---------------------------------------------------------------------------
// Kernel 1: h = x @ W^T  (h row-major (ROWS,64)),  s_j = h · a_j
// (s_i dropped: softmax over j is invariant to the per-i constant.)
// ---------------------------------------------------------------------------
__global__ __launch_bounds__(256, 4) void fc_kernel(
    const float* __restrict__ x, const float* __restrict__ W,
    const float* __restrict__ attn_w,
    float* __restrict__ h, float* __restrict__ sj)
{
    __shared__ float  xs[8 * IN_DIM];   // 4 KB
    __shared__ float4 ws[64 * 33];      // 33.8 KB (padded W, conflict-floor)
    const int t    = threadIdx.x;
    const int lane = t & 63;
    const int w    = t >> 6;
    const int rowBase = blockIdx.x * 8;

    ((float4*)xs)[t] = ((const float4*)(x + (size_t)rowBase * IN_DIM))[t];
    const float4* W4 = (const float4*)W;          // 2048 float4, coalesced
    #pragma unroll
    for (int i = 0; i < 8; ++i) {
        const int s = t + i * 256;
        ws[(s >> 5) * 33 + (s & 31)] = W4[s];
    }
    const float a_j = attn_w[OUT_DIM + lane];
    __syncthreads();

    const float4* xr0 = (const float4*)&xs[(w * 2 + 0) * IN_DIM];
    const float4* xr1 = (const float4*)&xs[(w * 2 + 1) * IN_DIM];
    float acc0 = 0.f, acc1 = 0.f;
    #pragma unroll 8
    for (int k = 0; k < IN_DIM / 4; ++k) {
        const float4 wv = ws[lane * 33 + k];
        const float4 x0 = xr0[k];
        const float4 x1 = xr1[k];
        acc0 += x0.x * wv.x + x0.y * wv.y + x0.z * wv.z + x0.w * wv.w;
        acc1 += x1.x * wv.x + x1.y * wv.y + x1.z * wv.z + x1.w * wv.w;
    }
    #pragma unroll
    for (int r = 0; r < 2; ++r) {
        const float a   = r ? acc1 : acc0;
        const int   row = rowBase + w * 2 + r;
        h[(size_t)row * OUT_DIM + lane] = a;
        float pj = a * a_j;
        #pragma unroll
        for (int m = 32; m > 0; m >>= 1) pj += __shfl_xor(pj, m, 64);
        if (lane == 0) sj[row] = pj;
    }
}

// ---------------------------------------------------------------------------
// Kernel 2: TI=4 rows per block, wave w owns row w (softmax barrier-free,
// row-sum stays in registers; normalization folded into the epilogue).
// 1024 blocks x 256 thr, 26 KB LDS -> 4 blocks/CU = 16 waves/CU.
// Edge loads fully coalesced: 1 KiB contiguous per wave instruction
// (4 lanes per j, quad shfl reduce for the 16-wide edge dot).
// Phase 3 reads h once per block (128 MB total L2 traffic at TI=4).
// ---------------------------------------------------------------------------
__global__ __launch_bounds__(256, 4) void attn_kernel(
    const float* __restrict__ edge, const float* __restrict__ attn_w,
    const float* __restrict__ h, const float* __restrict__ sj,
    float* __restrict__ out)
{
    __shared__ float  sjb[NN];            // 2 KB
    __shared__ float  alpha[TI * NN];     // 8 KB (e, then unnormalized p)
    __shared__ float4 part[TI][16][16];   // 16 KB

    const int t    = threadIdx.x;
    const int lane = t & 63;
    const int w    = t >> 6;              // wave = local row r
    const int blk  = blockIdx.x;
    const int b    = blk >> 7;            // 128 tiles per batch
    const int itile = blk & 127;
    const size_t rowg = ((size_t)b << 9) + itile * TI + w;

    if (t < 128)                          // stage s_j for the whole batch
        ((float4*)sjb)[t] = ((const float4*)(sj + ((size_t)b << 9)))[t];

    const float4 aesel = ((const float4*)(attn_w + 2 * OUT_DIM))[lane & 3];
    const float4* ef4 = (const float4*)edge + rowg * (NN * EDGE_DIM / 4);
    __syncthreads();                      // sjb ready

    // ---- phase 1: e_j for this wave's row; 16 j per iteration ----
    const int jq = lane >> 2;             // 0..15: which j in the 16-group
    const int q  = lane & 3;              // quarter of the 16-wide edge vec
    float m = -1e30f;
    #pragma unroll 4
    for (int it = 0; it < 32; ++it) {
        const int j = it * 16 + jq;
        const float4 v = ef4[j * 4 + q];  // wave: 1 KiB contiguous
        float pd = v.x * aesel.x + v.y * aesel.y + v.z * aesel.z + v.w * aesel.w;
        pd += __shfl_xor(pd, 1, 64);
        pd += __shfl_xor(pd, 2, 64);      // all 4 quad lanes hold full dot
        const float ev = pd + sjb[j];
        m = fmaxf(m, ev);
        if (q == 0) alpha[w * NN + j] = ev;   // 16 consecutive banks
    }
    #pragma unroll
    for (int msk = 4; msk < 64; msk <<= 1) m = fmaxf(m, __shfl_xor(m, msk, 64));

    // ---- pass 2 (wave-local, no barrier): p = exp(e-m), keep sum in regs ----
    float s = 0.f;
    #pragma unroll
    for (int k = 0; k < 8; ++k) {
        const int idx = w * NN + k * 64 + lane;
        const float p = __expf(alpha[idx] - m);
        alpha[idx] = p;                   // left UNnormalized
        s += p;
    }
    #pragma unroll
    for (int msk = 1; msk < 64; msk <<= 1) s += __shfl_xor(s, msk, 64);
    const float rinv = 1.0f / s;          // wave w holds row w's 1/sum

    __syncthreads();                      // all alpha rows visible

    // ---- phase 3: out[r,:] = sum_j p[r][j] * h[b,j,:], h read once ----
    const int o4 = t & 15;                // float4 chunk of 64-dim output
    const int g  = t >> 4;                // 16 groups over j
    const float4* h4 = (const float4*)(h + (((size_t)b) << 9) * OUT_DIM);
    float4 acc[TI];
    #pragma unroll
    for (int r = 0; r < TI; ++r) acc[r] = make_float4(0.f, 0.f, 0.f, 0.f);
    #pragma unroll 4
    for (int j = g; j < NN; j += 16) {
        const float4 hv = h4[j * 16 + o4];
        #pragma unroll
        for (int r = 0; r < TI; ++r) {
            const float a = alpha[r * NN + j];   // 16-lane broadcast
            acc[r].x += a * hv.x; acc[r].y += a * hv.y;
            acc[r].z += a * hv.z; acc[r].w += a * hv.w;
        }
    }
    #pragma unroll
    for (int r = 0; r < TI; ++r) part[r][g][o4] = acc[r];
    __syncthreads();

    // ---- epilogue: wave w reduces row w; fold softmax norm (rinv) ----
    {
        const int c  = lane & 15;         // output float4 chunk
        const int q2 = lane >> 4;         // quarter of the 16 groups
        float4 v = part[w][q2 * 4 + 0][c];
        #pragma unroll
        for (int i = 1; i < 4; ++i) {
            const float4 u = part[w][q2 * 4 + i][c];
            v.x += u.x; v.y += u.y; v.z += u.z; v.w += u.w;
        }
        #pragma unroll
        for (int msk = 16; msk <= 32; msk <<= 1) {
            v.x += __shfl_xor(v.x, msk, 64);
            v.y += __shfl_xor(v.y, msk, 64);
            v.z += __shfl_xor(v.z, msk, 64);
            v.w += __shfl_xor(v.w, msk, 64);
        }
        if (q2 == 0) {
            v.x *= rinv; v.y *= rinv; v.z *= rinv; v.w *= rinv;
            ((float4*)out)[rowg * 16 + c] = v;   // 256 B/wave coalesced
        }
    }
}

extern "C" void kernel_launch(void* const* d_in, const int* in_sizes, int n_in,
                              void* d_out, int out_size, void* d_ws, size_t ws_size,
                              hipStream_t stream) {
    const float* x      = (const float*)d_in[0];
    const float* edge   = (const float*)d_in[1];
    const float* W_fc   = (const float*)d_in[2];
    const float* attn_w = (const float*)d_in[3];
    float* out = (float*)d_out;

    float* h  = (float*)d_ws;                   // ROWS*64 floats = 1 MiB
    float* sj = h + (size_t)ROWS * OUT_DIM;     // 16 KB

    fc_kernel<<<ROWS / 8, 256, 0, stream>>>(x, W_fc, attn_w, h, sj);
    attn_kernel<<<ROWS / TI, 256, 0, stream>>>(edge, attn_w, h, sj, out);
}